// Round 1
// baseline (208.187 us; speedup 1.0000x reference)
//
#include <hip/hip_runtime.h>
#include <hip/hip_bf16.h>
#include <stdint.h>

#define N_HEADS 8
#define D_K 64
#define SCALE 0.125f

typedef __attribute__((ext_vector_type(4))) float f32x4;
typedef __attribute__((ext_vector_type(8))) short bf16x8;

#define AS1 __attribute__((address_space(1)))
#define AS3 __attribute__((address_space(3)))

static __device__ __forceinline__ void gload_lds16(const void* g, void* l) {
    __builtin_amdgcn_global_load_lds((const AS1 void*)g, (AS3 void*)l, 16, 0, 0);
}

static __device__ __forceinline__ __hip_bfloat16 f2bf(float f) {
    return __float2bfloat16(f);
}

// ---------------------------------------------------------------------------
// Generic batched transpose + fp32->bf16 convert.
// in:  (Bt, R, C) f32, out: (Bt, C, R) bf16, out[b][c][r] = in[b][r][c].
// grid: (C/32, R/32, Bt), block: (32, 8). R, C multiples of 32.
// ---------------------------------------------------------------------------
__global__ void transpose_bf16(const float* __restrict__ in,
                               __hip_bfloat16* __restrict__ out,
                               int R, int C) {
    __shared__ float tile[32][33];
    const int bz = blockIdx.z;
    const int r0 = blockIdx.y * 32, c0 = blockIdx.x * 32;
    const float* ip = in + (size_t)bz * R * C;
    __hip_bfloat16* op = out + (size_t)bz * R * C;
    const int tx = threadIdx.x, ty = threadIdx.y;
#pragma unroll
    for (int i = 0; i < 4; ++i)
        tile[ty + i * 8][tx] = ip[(size_t)(r0 + ty + i * 8) * C + c0 + tx];
    __syncthreads();
#pragma unroll
    for (int i = 0; i < 4; ++i)
        op[(size_t)(c0 + ty + i * 8) * R + r0 + tx] = f2bf(tile[tx][ty + i * 8]);
}

// ---------------------------------------------------------------------------
// 128x128 GEMM tile core (m97 structure): D[m][n] = sum_k A[m][k] * BT[n][k].
// A: (Mtile=128 rows) x K bf16 row-major, lda elements.
// BT: (Ntile=128 rows) x K bf16 row-major, ldb elements.
// 256 threads = 4 waves (2x2), each wave 64x64 = 4x4 fragments of 16x16.
// D layout per fragment: col = lane&15, row = (lane>>4)*4 + reg  [m89-verified].
// ---------------------------------------------------------------------------
__device__ __forceinline__ void gemm128_tile(
    const __hip_bfloat16* __restrict__ Abase, int lda,
    const __hip_bfloat16* __restrict__ Bbase, int ldb,
    int K,
    __hip_bfloat16* Atile, __hip_bfloat16* Btile,
    f32x4 (&acc)[4][4]) {
    const int t = threadIdx.x;
    const int w = t >> 6;
    const int l = t & 63;
    const int wr = (w >> 1) * 64, wc = (w & 1) * 64;
    const int fr = l & 15, fq = l >> 4;

#pragma unroll
    for (int m = 0; m < 4; ++m)
#pragma unroll
        for (int n = 0; n < 4; ++n) acc[m][n] = (f32x4)0.f;

    for (int k0 = 0; k0 < K; k0 += 64) {
        __syncthreads();  // previous iteration's LDS reads done before overwrite
        // Stage A/B tiles: 128 rows x 64 bf16 (128 B/row) each, width-16 DMA.
#pragma unroll
        for (int i = 0; i < 4; ++i) {
            const int tt = t + i * 256;
            const int row = tt >> 3, c16 = tt & 7;
            const char* ga = (const char*)(Abase + (size_t)row * lda + k0) + c16 * 16;
            const char* gb = (const char*)(Bbase + (size_t)row * ldb + k0) + c16 * 16;
            char* la = (char*)Atile + w * 1024 + i * 4096;  // wave-uniform base
            char* lb = (char*)Btile + w * 1024 + i * 4096;
            gload_lds16(ga, la);
            gload_lds16(gb, lb);
        }
        __syncthreads();
#pragma unroll
        for (int kb = 0; kb < 2; ++kb) {
            bf16x8 af[4], bfr[4];
#pragma unroll
            for (int m = 0; m < 4; ++m)
                af[m] = *(const bf16x8*)(Atile + (wr + m * 16 + fr) * 64 + kb * 32 + fq * 8);
#pragma unroll
            for (int n = 0; n < 4; ++n)
                bfr[n] = *(const bf16x8*)(Btile + (wc + n * 16 + fr) * 64 + kb * 32 + fq * 8);
#pragma unroll
            for (int m = 0; m < 4; ++m)
#pragma unroll
                for (int n = 0; n < 4; ++n)
                    acc[m][n] = __builtin_amdgcn_mfma_f32_16x16x32_bf16(af[m], bfr[n], acc[m][n], 0, 0, 0);
        }
    }
}

// ---------------------------------------------------------------------------
// QKV GEMM: D[n][j] = xt[b][n][:] . Wqt[j][:], + bias; scatter to q/k/v ws.
// q_ws,k_ws: (B*8, 1024, 64) bf16 (SCALE folded into q). v_ws: (B*8, 64, 1024).
// grid: (12, 8, 16)
// ---------------------------------------------------------------------------
__global__ __launch_bounds__(256) void qkv_gemm(
    const __hip_bfloat16* __restrict__ xt,   // (B, 1024, 512)
    const __hip_bfloat16* __restrict__ Wqt,  // (1536, 512)
    const float* __restrict__ bias,          // (1536)
    __hip_bfloat16* __restrict__ q_ws,
    __hip_bfloat16* __restrict__ k_ws,
    __hip_bfloat16* __restrict__ v_ws) {
    __shared__ __attribute__((aligned(16))) __hip_bfloat16 Atile[128 * 64];
    __shared__ __attribute__((aligned(16))) __hip_bfloat16 Btile[128 * 64];
    const int tn = blockIdx.x;  // j-tile 0..11
    const int tm = blockIdx.y;  // n-tile 0..7
    const int b  = blockIdx.z;
    f32x4 acc[4][4];
    gemm128_tile(xt + ((size_t)b * 1024 + tm * 128) * 512, 512,
                 Wqt + (size_t)tn * 128 * 512, 512, 512, Atile, Btile, acc);

    const int t = threadIdx.x, l = t & 63, w = t >> 6;
    const int wr = (w >> 1) * 64, wc = (w & 1) * 64, fr = l & 15, fq = l >> 4;
#pragma unroll
    for (int m = 0; m < 4; ++m) {
#pragma unroll
        for (int n = 0; n < 4; ++n) {
            const int j = tn * 128 + wc + n * 16 + fr;  // 16-col fragment never straddles a 64-part boundary
            const int h = j / 192, rem = j % 192, p = rem / 64, d = rem % 64;
            const float bj = bias[j];
            const size_t bh = (size_t)b * 8 + h;
#pragma unroll
            for (int r = 0; r < 4; ++r) {
                const int nn = tm * 128 + wr + m * 16 + fq * 4 + r;  // token index
                const float v = acc[m][n][r] + bj;
                if (p == 0)      q_ws[(bh * 1024 + nn) * 64 + d] = f2bf(v * SCALE);
                else if (p == 1) k_ws[(bh * 1024 + nn) * 64 + d] = f2bf(v);
                else             v_ws[(bh * 64 + d) * 1024 + nn] = f2bf(v);
            }
        }
    }
}

// ---------------------------------------------------------------------------
// Flash attention. Block = (b,h) x 64-row Q tile; 4 waves x 16 rows.
// KV tiles of 64 staged in LDS (XOR swizzled). grid: (16, 128), 256 thr.
// ao: (B, 1024, 512) bf16.
// ---------------------------------------------------------------------------
__global__ __launch_bounds__(256) void attn_kernel(
    const __hip_bfloat16* __restrict__ q_ws,
    const __hip_bfloat16* __restrict__ k_ws,
    const __hip_bfloat16* __restrict__ v_ws,  // (BH, 64, 1024) d-major
    __hip_bfloat16* __restrict__ ao) {
    __shared__ __attribute__((aligned(16))) __hip_bfloat16 Kt[64 * 64];  // [key][kdim], swizzled
    __shared__ __attribute__((aligned(16))) __hip_bfloat16 Vt[64 * 64];  // [d][key], swizzled
    __shared__ __attribute__((aligned(16))) __hip_bfloat16 Pl[4][16 * 64];  // per-wave P, swizzled

    const int qt = blockIdx.x;   // 0..15
    const int bh = blockIdx.y;   // b*8 + h
    const int t = threadIdx.x, l = t & 63, w = t >> 6;
    const int fr = l & 15, fq = l >> 4;
    const int q0 = qt * 64 + w * 16;

    // Q strip (16x64) -> A-fragments, kept in registers. SCALE pre-folded.
    const __hip_bfloat16* qp = q_ws + ((size_t)bh * 1024 + q0) * 64;
    bf16x8 qa[2];
    qa[0] = *(const bf16x8*)(qp + fr * 64 + fq * 8);
    qa[1] = *(const bf16x8*)(qp + fr * 64 + 32 + fq * 8);

    f32x4 o[4];
#pragma unroll
    for (int i = 0; i < 4; ++i) o[i] = (f32x4)0.f;
    float mrow[4], lrow[4];
#pragma unroll
    for (int r = 0; r < 4; ++r) { mrow[r] = -1e30f; lrow[r] = 0.f; }

    const __hip_bfloat16* kbase = k_ws + (size_t)bh * 1024 * 64;
    const __hip_bfloat16* vbase = v_ws + (size_t)bh * 64 * 1024;

    for (int kt = 0; kt < 16; ++kt) {
        __syncthreads();
        // Stage K (64x64, key-major) and Vt (64x64, d-major) with XOR swizzle.
        {
            const __hip_bfloat16* kp = kbase + (size_t)kt * 64 * 64;
            const __hip_bfloat16* vp = vbase + kt * 64;
#pragma unroll
            for (int i = 0; i < 2; ++i) {
                const int tt = t + i * 256;
                const int row = tt >> 3, c16 = tt & 7;
                const int a = (row * 128 + c16 * 16) ^ ((row & 7) << 4);
                bf16x8 kv = *(const bf16x8*)(kp + row * 64 + c16 * 8);
                *(bf16x8*)((char*)Kt + a) = kv;
                bf16x8 vv = *(const bf16x8*)(vp + (size_t)row * 1024 + c16 * 8);
                *(bf16x8*)((char*)Vt + a) = vv;
            }
        }
        __syncthreads();

        // S = Q @ K^T : 16 x 64 per wave (4 fragments over keys).
        f32x4 s[4];
#pragma unroll
        for (int f = 0; f < 4; ++f) s[f] = (f32x4)0.f;
#pragma unroll
        for (int kb = 0; kb < 2; ++kb) {
#pragma unroll
            for (int f = 0; f < 4; ++f) {
                const int key = f * 16 + fr;
                const int a = (key * 128 + kb * 64 + fq * 16) ^ ((key & 7) << 4);
                bf16x8 kf = *(const bf16x8*)((char*)Kt + a);
                s[f] = __builtin_amdgcn_mfma_f32_16x16x32_bf16(qa[kb], kf, s[f], 0, 0, 0);
            }
        }

        // Online softmax. Lane owns rows fq*4+r, cols fr across 4 fragments.
        float pf[4][4];
#pragma unroll
        for (int r = 0; r < 4; ++r) {
            float mx = fmaxf(fmaxf(s[0][r], s[1][r]), fmaxf(s[2][r], s[3][r]));
#pragma unroll
            for (int mask = 1; mask < 16; mask <<= 1) mx = fmaxf(mx, __shfl_xor(mx, mask, 64));
            const float mn = fmaxf(mrow[r], mx);
            const float corr = __expf(mrow[r] - mn);
            mrow[r] = mn;
            float rs = 0.f;
#pragma unroll
            for (int f = 0; f < 4; ++f) {
                const float p = __expf(s[f][r] - mn);
                pf[f][r] = p;
                rs += p;
            }
#pragma unroll
            for (int mask = 1; mask < 16; mask <<= 1) rs += __shfl_xor(rs, mask, 64);
            lrow[r] = lrow[r] * corr + rs;
#pragma unroll
            for (int df = 0; df < 4; ++df) o[df][r] *= corr;
        }

        // P -> per-wave LDS (swizzled), then PV MFMA.
        __hip_bfloat16* pw = &Pl[w][0];
#pragma unroll
        for (int r = 0; r < 4; ++r) {
            const int prow = fq * 4 + r;
#pragma unroll
            for (int f = 0; f < 4; ++f) {
                const int a = (prow * 128 + (f * 16 + fr) * 2) ^ ((prow & 7) << 4);
                *(__hip_bfloat16*)((char*)pw + a) = f2bf(pf[f][r]);
            }
        }
        // LDS ops within a wave are in-order; Pl is wave-private.
#pragma unroll
        for (int kb = 0; kb < 2; ++kb) {
            const int pa = (fr * 128 + kb * 64 + fq * 16) ^ ((fr & 7) << 4);
            bf16x8 pfrag = *(const bf16x8*)((char*)pw + pa);
#pragma unroll
            for (int df = 0; df < 4; ++df) {
                const int d = df * 16 + fr;
                const int va = (d * 128 + kb * 64 + fq * 16) ^ ((d & 7) << 4);
                bf16x8 vb = *(const bf16x8*)((char*)Vt + va);
                o[df] = __builtin_amdgcn_mfma_f32_16x16x32_bf16(pfrag, vb, o[df], 0, 0, 0);
            }
        }
    }

    // Normalize and store: ao[b][n][h*64+d].
    const int b = bh >> 3, h = bh & 7;
#pragma unroll
    for (int r = 0; r < 4; ++r) {
        const float inv = 1.f / lrow[r];
        const int n = q0 + fq * 4 + r;
#pragma unroll
        for (int df = 0; df < 4; ++df) {
            const int d = df * 16 + fr;
            ao[((size_t)b * 1024 + n) * 512 + h * 64 + d] = f2bf(o[df][r] * inv);
        }
    }
}

// ---------------------------------------------------------------------------
// Out projection + bias + residual, directly in (B, C, N) layout:
// out[b][c][n] = sum_i Wot[c][i] * ao[b][n][i] + b_out[c] + x[b][c][n].
// grid: (8, 4, 16)
// ---------------------------------------------------------------------------
__global__ __launch_bounds__(256) void out_gemm(
    const __hip_bfloat16* __restrict__ Wot,  // (512 c, 512 i)
    const __hip_bfloat16* __restrict__ ao,   // (B, 1024, 512)
    const float* __restrict__ bias,          // (512)
    const float* __restrict__ x,             // (B, 512, 1024)
    float* __restrict__ out) {               // (B, 512, 1024)
    __shared__ __attribute__((aligned(16))) __hip_bfloat16 Atile[128 * 64];
    __shared__ __attribute__((aligned(16))) __hip_bfloat16 Btile[128 * 64];
    const int tn = blockIdx.x;  // n-tile 0..7
    const int tc = blockIdx.y;  // c-tile 0..3
    const int b  = blockIdx.z;
    f32x4 acc[4][4];
    gemm128_tile(Wot + (size_t)tc * 128 * 512, 512,
                 ao + ((size_t)b * 1024 + tn * 128) * 512, 512, 512, Atile, Btile, acc);

    const int t = threadIdx.x, l = t & 63, w = t >> 6;
    const int wr = (w >> 1) * 64, wc = (w & 1) * 64, fr = l & 15, fq = l >> 4;
#pragma unroll
    for (int m = 0; m < 4; ++m) {
#pragma unroll
        for (int n = 0; n < 4; ++n) {
            const int nn = tn * 128 + wc + n * 16 + fr;  // token col
#pragma unroll
            for (int r = 0; r < 4; ++r) {
                const int c = tc * 128 + wr + m * 16 + fq * 4 + r;  // channel row
                const size_t idx = ((size_t)b * 512 + c) * 1024 + nn;
                out[idx] = acc[m][n][r] + bias[c] + x[idx];
            }
        }
    }
}

// ---------------------------------------------------------------------------
extern "C" void kernel_launch(void* const* d_in, const int* in_sizes, int n_in,
                              void* d_out, int out_size, void* d_ws, size_t ws_size,
                              hipStream_t stream) {
    const float* x     = (const float*)d_in[0];  // (16, 512, 32, 32)
    const float* W_qkv = (const float*)d_in[1];  // (512, 1536)
    const float* b_qkv = (const float*)d_in[2];  // (1536)
    const float* W_out = (const float*)d_in[3];  // (512, 512)
    const float* b_out = (const float*)d_in[4];  // (512)
    float* out = (float*)d_out;

    const int B = 16, C = 512, N = 1024, BH = B * N_HEADS;

    char* ws = (char*)d_ws;
    __hip_bfloat16* xt   = (__hip_bfloat16*)ws; ws += (size_t)B * N * C * 2;        // 16 MB
    __hip_bfloat16* Wqt  = (__hip_bfloat16*)ws; ws += (size_t)1536 * 512 * 2;       // 1.5 MB
    __hip_bfloat16* Wot  = (__hip_bfloat16*)ws; ws += (size_t)512 * 512 * 2;        // 0.5 MB
    __hip_bfloat16* q_ws = (__hip_bfloat16*)ws; ws += (size_t)BH * N * 64 * 2;      // 16 MB
    __hip_bfloat16* k_ws = (__hip_bfloat16*)ws; ws += (size_t)BH * N * 64 * 2;      // 16 MB
    __hip_bfloat16* v_ws = (__hip_bfloat16*)ws; ws += (size_t)BH * 64 * N * 2;      // 16 MB
    __hip_bfloat16* ao   = (__hip_bfloat16*)ws; ws += (size_t)B * N * 512 * 2;      // 16 MB

    // Prep: transposes + bf16 conversion.
    transpose_bf16<<<dim3(N / 32, C / 32, B), dim3(32, 8), 0, stream>>>(x, xt, C, N);
    transpose_bf16<<<dim3(1536 / 32, 512 / 32, 1), dim3(32, 8), 0, stream>>>(W_qkv, Wqt, 512, 1536);
    transpose_bf16<<<dim3(512 / 32, 512 / 32, 1), dim3(32, 8), 0, stream>>>(W_out, Wot, 512, 512);

    // QKV projection.
    qkv_gemm<<<dim3(12, 8, B), 256, 0, stream>>>(xt, Wqt, b_qkv, q_ws, k_ws, v_ws);

    // Flash attention.
    attn_kernel<<<dim3(16, BH), 256, 0, stream>>>(q_ws, k_ws, v_ws, ao);

    // Output projection + residual (+implicit transpose back to (B,C,H,W)).
    out_gemm<<<dim3(8, 4, B), 256, 0, stream>>>(Wot, ao, b_out, x, out);
}

// Round 4
// 186.618 us; speedup vs baseline: 1.1156x; 1.1156x over previous
//
#include <hip/hip_runtime.h>
#include <hip/hip_bf16.h>
#include <stdint.h>

#define N_HEADS 8
#define D_K 64
#define SCALE 0.125f  // power of two: folding into q's bf16 is lossless

typedef __attribute__((ext_vector_type(4))) float f32x4;
typedef __attribute__((ext_vector_type(16))) float f32x16;
typedef __attribute__((ext_vector_type(8))) short bf16x8;
typedef __attribute__((ext_vector_type(4))) unsigned short u16x4;

#define AS1 __attribute__((address_space(1)))
#define AS3 __attribute__((address_space(3)))

static __device__ __forceinline__ void gload_lds16(const void* g, void* l) {
    __builtin_amdgcn_global_load_lds((const AS1 void*)g, (AS3 void*)l, 16, 0, 0);
}

static __device__ __forceinline__ __hip_bfloat16 f2bf(float f) {
    return __float2bfloat16(f);
}

static __device__ __forceinline__ unsigned short bfbits(float f) {
    return __builtin_bit_cast(unsigned short, __float2bfloat16(f));
}

static __device__ __forceinline__ uint32_t pkbf(float lo, float hi) {
    return (uint32_t)bfbits(lo) | ((uint32_t)bfbits(hi) << 16);
}

// ---------------------------------------------------------------------------
// Generic batched transpose + fp32->bf16 convert.
// ---------------------------------------------------------------------------
__global__ void transpose_bf16(const float* __restrict__ in,
                               __hip_bfloat16* __restrict__ out,
                               int R, int C) {
    __shared__ float tile[32][33];
    const int bz = blockIdx.z;
    const int r0 = blockIdx.y * 32, c0 = blockIdx.x * 32;
    const float* ip = in + (size_t)bz * R * C;
    __hip_bfloat16* op = out + (size_t)bz * R * C;
    const int tx = threadIdx.x, ty = threadIdx.y;
#pragma unroll
    for (int i = 0; i < 4; ++i)
        tile[ty + i * 8][tx] = ip[(size_t)(r0 + ty + i * 8) * C + c0 + tx];
    __syncthreads();
#pragma unroll
    for (int i = 0; i < 4; ++i)
        op[(size_t)(c0 + ty + i * 8) * R + r0 + tx] = f2bf(tile[tx][ty + i * 8]);
}

// ---------------------------------------------------------------------------
// 128x128 GEMM tile core (m97 structure).
// ---------------------------------------------------------------------------
__device__ __forceinline__ void gemm128_tile(
    const __hip_bfloat16* __restrict__ Abase, int lda,
    const __hip_bfloat16* __restrict__ Bbase, int ldb,
    int K,
    __hip_bfloat16* Atile, __hip_bfloat16* Btile,
    f32x4 (&acc)[4][4]) {
    const int t = threadIdx.x;
    const int w = t >> 6;
    const int l = t & 63;
    const int wr = (w >> 1) * 64, wc = (w & 1) * 64;
    const int fr = l & 15, fq = l >> 4;

#pragma unroll
    for (int m = 0; m < 4; ++m)
#pragma unroll
        for (int n = 0; n < 4; ++n) acc[m][n] = (f32x4)0.f;

    for (int k0 = 0; k0 < K; k0 += 64) {
        __syncthreads();
#pragma unroll
        for (int i = 0; i < 4; ++i) {
            const int tt = t + i * 256;
            const int row = tt >> 3, c16 = tt & 7;
            const char* ga = (const char*)(Abase + (size_t)row * lda + k0) + c16 * 16;
            const char* gb = (const char*)(Bbase + (size_t)row * ldb + k0) + c16 * 16;
            char* la = (char*)Atile + w * 1024 + i * 4096;
            char* lb = (char*)Btile + w * 1024 + i * 4096;
            gload_lds16(ga, la);
            gload_lds16(gb, lb);
        }
        __syncthreads();
#pragma unroll
        for (int kb = 0; kb < 2; ++kb) {
            bf16x8 af[4], bfr[4];
#pragma unroll
            for (int m = 0; m < 4; ++m)
                af[m] = *(const bf16x8*)(Atile + (wr + m * 16 + fr) * 64 + kb * 32 + fq * 8);
#pragma unroll
            for (int n = 0; n < 4; ++n)
                bfr[n] = *(const bf16x8*)(Btile + (wc + n * 16 + fr) * 64 + kb * 32 + fq * 8);
#pragma unroll
            for (int m = 0; m < 4; ++m)
#pragma unroll
                for (int n = 0; n < 4; ++n)
                    acc[m][n] = __builtin_amdgcn_mfma_f32_16x16x32_bf16(af[m], bfr[n], acc[m][n], 0, 0, 0);
        }
    }
}

// ---------------------------------------------------------------------------
// QKV GEMM + scatter. q gets SCALE (=0.125, exact) folded.
// ---------------------------------------------------------------------------
__global__ __launch_bounds__(256) void qkv_gemm(
    const __hip_bfloat16* __restrict__ xt,   // (B, 1024, 512)
    const __hip_bfloat16* __restrict__ Wqt,  // (1536, 512)
    const float* __restrict__ bias,          // (1536)
    __hip_bfloat16* __restrict__ q_ws,
    __hip_bfloat16* __restrict__ k_ws,
    __hip_bfloat16* __restrict__ v_ws) {
    __shared__ __attribute__((aligned(16))) __hip_bfloat16 Atile[128 * 64];
    __shared__ __attribute__((aligned(16))) __hip_bfloat16 Btile[128 * 64];
    const int tn = blockIdx.x;  // j-tile 0..11
    const int tm = blockIdx.y;  // n-tile 0..7
    const int b  = blockIdx.z;
    f32x4 acc[4][4];
    gemm128_tile(xt + ((size_t)b * 1024 + tm * 128) * 512, 512,
                 Wqt + (size_t)tn * 128 * 512, 512, 512, Atile, Btile, acc);

    const int t = threadIdx.x, l = t & 63, w = t >> 6;
    const int wr = (w >> 1) * 64, wc = (w & 1) * 64, fr = l & 15, fq = l >> 4;
#pragma unroll
    for (int m = 0; m < 4; ++m) {
#pragma unroll
        for (int n = 0; n < 4; ++n) {
            const int j = tn * 128 + wc + n * 16 + fr;
            const int h = j / 192, rem = j % 192, p = rem / 64, d = rem % 64;
            const float bj = bias[j];
            const size_t bh = (size_t)b * 8 + h;
#pragma unroll
            for (int r = 0; r < 4; ++r) {
                const int nn = tm * 128 + wr + m * 16 + fq * 4 + r;
                const float v = acc[m][n][r] + bj;
                if (p == 0)      q_ws[(bh * 1024 + nn) * 64 + d] = f2bf(v * SCALE);
                else if (p == 1) k_ws[(bh * 1024 + nn) * 64 + d] = f2bf(v);
                else             v_ws[(bh * 64 + d) * 1024 + nn] = f2bf(v);
            }
        }
    }
}

// ---------------------------------------------------------------------------
// Flash attention, swapped-QK^T (S^T = K.Q^T via 32x32x16) with lane-local
// softmax. NO permlane asm this round: pair-combine via __shfl_xor(.,32),
// P routed through a per-wave swizzled LDS buffer (verified primitive
// patterns only) to isolate the round-2/3 failure to the permlane path.
// Block: 128 q rows (4 waves x 32). grid (8, 128), 256 thr.
// ---------------------------------------------------------------------------
__global__ __launch_bounds__(256) void attn_kernel(
    const __hip_bfloat16* __restrict__ q_ws,  // (BH,1024,64), SCALE folded
    const __hip_bfloat16* __restrict__ k_ws,  // (BH,1024,64)
    const __hip_bfloat16* __restrict__ v_ws,  // (BH,64,1024) d-major
    __hip_bfloat16* __restrict__ ao) {        // (B,1024,512)
    __shared__ __attribute__((aligned(16))) __hip_bfloat16 Kt[64 * 64];     // [key][d], swizzled
    __shared__ __attribute__((aligned(16))) __hip_bfloat16 Vt[64 * 64];     // [d][key], swizzled
    __shared__ __attribute__((aligned(16))) __hip_bfloat16 Pl[4][32 * 64];  // per-wave [q][key], swizzled

    const int qt = blockIdx.x;   // 0..7
    const int bh = blockIdx.y;   // b*8 + h
    const int t = threadIdx.x, l = t & 63, w = t >> 6;
    const int lq = l & 31, hi = l >> 5;
    const int qrow = qt * 128 + w * 32 + lq;
    const int swz = (lq & 7) << 4;

    // Q B-fragment: lane (lq,hi) supplies Q[qrow][s*16 + hi*8 .. +7].
    const __hip_bfloat16* qp = q_ws + ((size_t)bh * 1024 + qrow) * 64;
    bf16x8 qb[4];
#pragma unroll
    for (int s = 0; s < 4; ++s) qb[s] = *(const bf16x8*)(qp + s * 16 + hi * 8);

    f32x16 oacc[2];
    oacc[0] = (f32x16)0.f; oacc[1] = (f32x16)0.f;
    float m = -1e30f, lsum = 0.f;

    const __hip_bfloat16* kbase = k_ws + (size_t)bh * 1024 * 64;
    const __hip_bfloat16* vbase = v_ws + (size_t)bh * 64 * 1024;
    __hip_bfloat16* pw = &Pl[w][0];

    for (int kt = 0; kt < 16; ++kt) {
        __syncthreads();
        // Stage K[64 key][64 d] and V^T[64 d][64 key], XOR-swizzled rows.
#pragma unroll
        for (int i = 0; i < 2; ++i) {
            const int tt = t + i * 256;
            const int row = tt >> 3, c16 = tt & 7;
            const int a = (row * 128 + c16 * 16) ^ ((row & 7) << 4);
            *(bf16x8*)((char*)Kt + a) =
                *(const bf16x8*)(kbase + (size_t)(kt * 64 + row) * 64 + c16 * 8);
            *(bf16x8*)((char*)Vt + a) =
                *(const bf16x8*)(vbase + (size_t)row * 1024 + kt * 64 + c16 * 8);
        }
        __syncthreads();

        // S^T[key][q] = K . Q^T. sacc[0]: keys 0-31, sacc[1]: keys 32-63.
        // Lane (lq,hi) holds S^T[krow][lq], krow = (reg&3)+8*(reg>>2)+4*hi.
        f32x16 sacc[2];
        sacc[0] = (f32x16)0.f; sacc[1] = (f32x16)0.f;
#pragma unroll
        for (int s = 0; s < 4; ++s) {
            const int colb = s * 32 + hi * 16;
            const int a0 = (lq * 128 + colb) ^ swz;
            const int a1 = ((32 + lq) * 128 + colb) ^ swz;
            bf16x8 k0 = *(const bf16x8*)((char*)Kt + a0);
            bf16x8 k1 = *(const bf16x8*)((char*)Kt + a1);
            sacc[0] = __builtin_amdgcn_mfma_f32_32x32x16_bf16(k0, qb[s], sacc[0], 0, 0, 0);
            sacc[1] = __builtin_amdgcn_mfma_f32_32x32x16_bf16(k1, qb[s], sacc[1], 0, 0, 0);
        }

        // Exact row max: 31 lane-local fmax + 1 shfl pair-combine (l ^ 32).
        float pmax = sacc[0][0];
#pragma unroll
        for (int i = 1; i < 16; ++i) pmax = fmaxf(pmax, sacc[0][i]);
#pragma unroll
        for (int i = 0; i < 16; ++i) pmax = fmaxf(pmax, sacc[1][i]);
        pmax = fmaxf(pmax, __shfl_xor(pmax, 32, 64));

        // Unconditional online-softmax rescale (round-1 numerics, P <= 1).
        const float mn = fmaxf(m, pmax);
        const float corr = __expf(m - mn);
        m = mn;
        lsum *= corr;
#pragma unroll
        for (int i = 0; i < 16; ++i) { oacc[0][i] *= corr; oacc[1][i] *= corr; }

        // P = exp(S - m); lane-partial sum.
#pragma unroll
        for (int ka = 0; ka < 2; ++ka)
#pragma unroll
            for (int i = 0; i < 16; ++i) {
                const float p = __expf(sacc[ka][i] - m);
                sacc[ka][i] = p;
                lsum += p;
            }

        // P -> per-wave LDS [q=lq][key], swizzled. Regs rq*4+0..3 map to
        // CONSECUTIVE keys kb..kb+3 (kb = ka*32 + rq*8 + hi*4): one b64 write.
#pragma unroll
        for (int ka = 0; ka < 2; ++ka)
#pragma unroll
            for (int rq = 0; rq < 4; ++rq) {
                uint2 val;
                val.x = pkbf(sacc[ka][rq * 4 + 0], sacc[ka][rq * 4 + 1]);
                val.y = pkbf(sacc[ka][rq * 4 + 2], sacc[ka][rq * 4 + 3]);
                const int kb = ka * 32 + rq * 8 + hi * 4;
                *(uint2*)((char*)pw + lq * 128 + ((kb * 2) ^ swz)) = val;
            }

        // PV: O^T[d][q] += V^T . P^T, 4 k-steps of 16 keys. B-frag read back
        // from Pl (wave-private; in-wave LDS ordering, no barrier needed).
#pragma unroll
        for (int s = 0; s < 4; ++s) {
            const int colb = s * 32 + hi * 16;
            bf16x8 pf = *(const bf16x8*)((char*)pw + lq * 128 + (colb ^ swz));
            const int va0 = (lq * 128 + colb) ^ swz;
            const int va1 = ((32 + lq) * 128 + colb) ^ swz;
            bf16x8 v0 = *(const bf16x8*)((char*)Vt + va0);
            bf16x8 v1 = *(const bf16x8*)((char*)Vt + va1);
            oacc[0] = __builtin_amdgcn_mfma_f32_32x32x16_bf16(v0, pf, oacc[0], 0, 0, 0);
            oacc[1] = __builtin_amdgcn_mfma_f32_32x32x16_bf16(v1, pf, oacc[1], 0, 0, 0);
        }
    }

    // Combine lane-partial sums across the (l, l^32) pair, normalize, store.
    lsum += __shfl_xor(lsum, 32, 64);
    const float inv = 1.f / lsum;
    const int b = bh >> 3, h = bh & 7;
    __hip_bfloat16* aop = ao + ((size_t)b * 1024 + qrow) * 512 + h * 64;
#pragma unroll
    for (int dd = 0; dd < 2; ++dd)
#pragma unroll
        for (int rg = 0; rg < 4; ++rg) {
            u16x4 pkd;
#pragma unroll
            for (int j = 0; j < 4; ++j)
                pkd[j] = bfbits(oacc[dd][rg * 4 + j] * inv);
            const int d0 = dd * 32 + rg * 8 + hi * 4;
            *(u16x4*)(aop + d0) = pkd;
        }
}

// ---------------------------------------------------------------------------
// Out projection + bias + residual in (B, C, N) layout.
// ---------------------------------------------------------------------------
__global__ __launch_bounds__(256) void out_gemm(
    const __hip_bfloat16* __restrict__ Wot,  // (512 c, 512 i)
    const __hip_bfloat16* __restrict__ ao,   // (B, 1024, 512)
    const float* __restrict__ bias,          // (512)
    const float* __restrict__ x,             // (B, 512, 1024)
    float* __restrict__ out) {               // (B, 512, 1024)
    __shared__ __attribute__((aligned(16))) __hip_bfloat16 Atile[128 * 64];
    __shared__ __attribute__((aligned(16))) __hip_bfloat16 Btile[128 * 64];
    const int tn = blockIdx.x;
    const int tc = blockIdx.y;
    const int b  = blockIdx.z;
    f32x4 acc[4][4];
    gemm128_tile(Wot + (size_t)tc * 128 * 512, 512,
                 ao + ((size_t)b * 1024 + tn * 128) * 512, 512, 512, Atile, Btile, acc);

    const int t = threadIdx.x, l = t & 63, w = t >> 6;
    const int wr = (w >> 1) * 64, wc = (w & 1) * 64, fr = l & 15, fq = l >> 4;
#pragma unroll
    for (int m = 0; m < 4; ++m) {
#pragma unroll
        for (int n = 0; n < 4; ++n) {
            const int nn = tn * 128 + wc + n * 16 + fr;
#pragma unroll
            for (int r = 0; r < 4; ++r) {
                const int c = tc * 128 + wr + m * 16 + fq * 4 + r;
                const size_t idx = ((size_t)b * 512 + c) * 1024 + nn;
                out[idx] = acc[m][n][r] + bias[c] + x[idx];
            }
        }
    }
}

// ---------------------------------------------------------------------------
extern "C" void kernel_launch(void* const* d_in, const int* in_sizes, int n_in,
                              void* d_out, int out_size, void* d_ws, size_t ws_size,
                              hipStream_t stream) {
    const float* x     = (const float*)d_in[0];
    const float* W_qkv = (const float*)d_in[1];
    const float* b_qkv = (const float*)d_in[2];
    const float* W_out = (const float*)d_in[3];
    const float* b_out = (const float*)d_in[4];
    float* out = (float*)d_out;

    const int B = 16, C = 512, N = 1024, BH = B * N_HEADS;

    char* ws = (char*)d_ws;
    __hip_bfloat16* xt   = (__hip_bfloat16*)ws; ws += (size_t)B * N * C * 2;
    __hip_bfloat16* Wqt  = (__hip_bfloat16*)ws; ws += (size_t)1536 * 512 * 2;
    __hip_bfloat16* Wot  = (__hip_bfloat16*)ws; ws += (size_t)512 * 512 * 2;
    __hip_bfloat16* q_ws = (__hip_bfloat16*)ws; ws += (size_t)BH * N * 64 * 2;
    __hip_bfloat16* k_ws = (__hip_bfloat16*)ws; ws += (size_t)BH * N * 64 * 2;
    __hip_bfloat16* v_ws = (__hip_bfloat16*)ws; ws += (size_t)BH * 64 * N * 2;
    __hip_bfloat16* ao   = (__hip_bfloat16*)ws; ws += (size_t)B * N * 512 * 2;

    transpose_bf16<<<dim3(N / 32, C / 32, B), dim3(32, 8), 0, stream>>>(x, xt, C, N);
    transpose_bf16<<<dim3(1536 / 32, 512 / 32, 1), dim3(32, 8), 0, stream>>>(W_qkv, Wqt, 512, 1536);
    transpose_bf16<<<dim3(512 / 32, 512 / 32, 1), dim3(32, 8), 0, stream>>>(W_out, Wot, 512, 512);

    qkv_gemm<<<dim3(12, 8, B), 256, 0, stream>>>(xt, Wqt, b_qkv, q_ws, k_ws, v_ws);

    attn_kernel<<<dim3(8, BH), 256, 0, stream>>>(q_ws, k_ws, v_ws, ao);

    out_gemm<<<dim3(8, 4, B), 256, 0, stream>>>(Wot, ao, b_out, x, out);
}

// Round 5
// 166.192 us; speedup vs baseline: 1.2527x; 1.1229x over previous
//
#include <hip/hip_runtime.h>
#include <hip/hip_bf16.h>
#include <stdint.h>

#define N_HEADS 8
#define D_K 64
#define SCALE 0.125f  // power of two: folding into q's bf16 is lossless

typedef __attribute__((ext_vector_type(4))) float f32x4;
typedef __attribute__((ext_vector_type(16))) float f32x16;
typedef __attribute__((ext_vector_type(8))) short bf16x8;
typedef __attribute__((ext_vector_type(4))) unsigned short u16x4;

#define AS1 __attribute__((address_space(1)))
#define AS3 __attribute__((address_space(3)))

static __device__ __forceinline__ void gload_lds16(const void* g, void* l) {
    __builtin_amdgcn_global_load_lds((const AS1 void*)g, (AS3 void*)l, 16, 0, 0);
}

static __device__ __forceinline__ __hip_bfloat16 f2bf(float f) {
    return __float2bfloat16(f);
}

static __device__ __forceinline__ unsigned short bfbits(float f) {
    return __builtin_bit_cast(unsigned short, __float2bfloat16(f));
}

static __device__ __forceinline__ uint32_t pkbf(float lo, float hi) {
    return (uint32_t)bfbits(lo) | ((uint32_t)bfbits(hi) << 16);
}

// ---------------------------------------------------------------------------
// Generic batched transpose + fp32->bf16 convert.
// ---------------------------------------------------------------------------
__global__ void transpose_bf16(const float* __restrict__ in,
                               __hip_bfloat16* __restrict__ out,
                               int R, int C) {
    __shared__ float tile[32][33];
    const int bz = blockIdx.z;
    const int r0 = blockIdx.y * 32, c0 = blockIdx.x * 32;
    const float* ip = in + (size_t)bz * R * C;
    __hip_bfloat16* op = out + (size_t)bz * R * C;
    const int tx = threadIdx.x, ty = threadIdx.y;
#pragma unroll
    for (int i = 0; i < 4; ++i)
        tile[ty + i * 8][tx] = ip[(size_t)(r0 + ty + i * 8) * C + c0 + tx];
    __syncthreads();
#pragma unroll
    for (int i = 0; i < 4; ++i)
        op[(size_t)(c0 + ty + i * 8) * R + r0 + tx] = f2bf(tile[tx][ty + i * 8]);
}

// ---------------------------------------------------------------------------
// 128x128 GEMM tile core (m97 structure). Unchanged (control).
// ---------------------------------------------------------------------------
__device__ __forceinline__ void gemm128_tile(
    const __hip_bfloat16* __restrict__ Abase, int lda,
    const __hip_bfloat16* __restrict__ Bbase, int ldb,
    int K,
    __hip_bfloat16* Atile, __hip_bfloat16* Btile,
    f32x4 (&acc)[4][4]) {
    const int t = threadIdx.x;
    const int w = t >> 6;
    const int l = t & 63;
    const int wr = (w >> 1) * 64, wc = (w & 1) * 64;
    const int fr = l & 15, fq = l >> 4;

#pragma unroll
    for (int m = 0; m < 4; ++m)
#pragma unroll
        for (int n = 0; n < 4; ++n) acc[m][n] = (f32x4)0.f;

    for (int k0 = 0; k0 < K; k0 += 64) {
        __syncthreads();
#pragma unroll
        for (int i = 0; i < 4; ++i) {
            const int tt = t + i * 256;
            const int row = tt >> 3, c16 = tt & 7;
            const char* ga = (const char*)(Abase + (size_t)row * lda + k0) + c16 * 16;
            const char* gb = (const char*)(Bbase + (size_t)row * ldb + k0) + c16 * 16;
            char* la = (char*)Atile + w * 1024 + i * 4096;
            char* lb = (char*)Btile + w * 1024 + i * 4096;
            gload_lds16(ga, la);
            gload_lds16(gb, lb);
        }
        __syncthreads();
#pragma unroll
        for (int kb = 0; kb < 2; ++kb) {
            bf16x8 af[4], bfr[4];
#pragma unroll
            for (int m = 0; m < 4; ++m)
                af[m] = *(const bf16x8*)(Atile + (wr + m * 16 + fr) * 64 + kb * 32 + fq * 8);
#pragma unroll
            for (int n = 0; n < 4; ++n)
                bfr[n] = *(const bf16x8*)(Btile + (wc + n * 16 + fr) * 64 + kb * 32 + fq * 8);
#pragma unroll
            for (int m = 0; m < 4; ++m)
#pragma unroll
                for (int n = 0; n < 4; ++n)
                    acc[m][n] = __builtin_amdgcn_mfma_f32_16x16x32_bf16(af[m], bfr[n], acc[m][n], 0, 0, 0);
        }
    }
}

// ---------------------------------------------------------------------------
// QKV GEMM + scatter. q gets SCALE (=0.125, exact) folded. Unchanged.
// ---------------------------------------------------------------------------
__global__ __launch_bounds__(256) void qkv_gemm(
    const __hip_bfloat16* __restrict__ xt,   // (B, 1024, 512)
    const __hip_bfloat16* __restrict__ Wqt,  // (1536, 512)
    const float* __restrict__ bias,          // (1536)
    __hip_bfloat16* __restrict__ q_ws,
    __hip_bfloat16* __restrict__ k_ws,
    __hip_bfloat16* __restrict__ v_ws) {
    __shared__ __attribute__((aligned(16))) __hip_bfloat16 Atile[128 * 64];
    __shared__ __attribute__((aligned(16))) __hip_bfloat16 Btile[128 * 64];
    const int tn = blockIdx.x;  // j-tile 0..11
    const int tm = blockIdx.y;  // n-tile 0..7
    const int b  = blockIdx.z;
    f32x4 acc[4][4];
    gemm128_tile(xt + ((size_t)b * 1024 + tm * 128) * 512, 512,
                 Wqt + (size_t)tn * 128 * 512, 512, 512, Atile, Btile, acc);

    const int t = threadIdx.x, l = t & 63, w = t >> 6;
    const int wr = (w >> 1) * 64, wc = (w & 1) * 64, fr = l & 15, fq = l >> 4;
#pragma unroll
    for (int m = 0; m < 4; ++m) {
#pragma unroll
        for (int n = 0; n < 4; ++n) {
            const int j = tn * 128 + wc + n * 16 + fr;
            const int h = j / 192, rem = j % 192, p = rem / 64, d = rem % 64;
            const float bj = bias[j];
            const size_t bh = (size_t)b * 8 + h;
#pragma unroll
            for (int r = 0; r < 4; ++r) {
                const int nn = tm * 128 + wr + m * 16 + fq * 4 + r;
                const float v = acc[m][n][r] + bj;
                if (p == 0)      q_ws[(bh * 1024 + nn) * 64 + d] = f2bf(v * SCALE);
                else if (p == 1) k_ws[(bh * 1024 + nn) * 64 + d] = f2bf(v);
                else             v_ws[(bh * 64 + d) * 1024 + nn] = f2bf(v);
            }
        }
    }
}

// ---------------------------------------------------------------------------
// Flash attention, swapped-QK^T + in-register softmax (round-4-verified math)
// with: 2-phase double-buffered K/V prefetch via global_load_lds with
// PRE-SWIZZLED global source (LDS linear, read-side XOR unchanged), one
// barrier per tile; quarter-P LDS buffer (1KB/wave); defer-max (T13, THR=8);
// setprio around MFMA; XCD-aware 1D grid (all q-tiles of a head -> same XCD).
// grid (1024), 256 thr.
// ---------------------------------------------------------------------------
__global__ __launch_bounds__(256) void attn_kernel(
    const __hip_bfloat16* __restrict__ q_ws,  // (BH,1024,64), SCALE folded
    const __hip_bfloat16* __restrict__ k_ws,  // (BH,1024,64)
    const __hip_bfloat16* __restrict__ v_ws,  // (BH,64,1024) d-major
    __hip_bfloat16* __restrict__ ao) {        // (B,1024,512)
    __shared__ __attribute__((aligned(16))) __hip_bfloat16 KtS[2][64 * 64];  // [key][d]
    __shared__ __attribute__((aligned(16))) __hip_bfloat16 VtS[2][64 * 64];  // [d][key]
    __shared__ __attribute__((aligned(16))) __hip_bfloat16 Pq[4][32 * 16];   // per-wave quarter-P

    const int id = blockIdx.x;
    const int bh = id & 127;   // id % 8 == bh % 8: one head's 8 q-tiles share an XCD
    const int qt = id >> 7;
    const int t = threadIdx.x, l = t & 63, w = t >> 6;
    const int lq = l & 31, hi = l >> 5;
    const int qrow = qt * 128 + w * 32 + lq;
    const int swz = (lq & 7) << 4;

    // Q B-fragment (registers): lane (lq,hi) supplies Q[qrow][s*16 + hi*8 ..].
    const __hip_bfloat16* qp = q_ws + ((size_t)bh * 1024 + qrow) * 64;
    bf16x8 qb[4];
#pragma unroll
    for (int s = 0; s < 4; ++s) qb[s] = *(const bf16x8*)(qp + s * 16 + hi * 8);

    f32x16 oacc[2];
    oacc[0] = (f32x16)0.f; oacc[1] = (f32x16)0.f;
    float m = -1e30f, lsum = 0.f;

    const __hip_bfloat16* kbase = k_ws + (size_t)bh * 1024 * 64;
    const __hip_bfloat16* vbase = v_ws + (size_t)bh * 64 * 1024;

    // DMA staging with pre-swizzled SOURCE: LDS linear slot s_lin of row gets
    // global 16B-slot (s_lin ^ (row&7)); reads use (row*128+c*16)^((row&7)<<4).
    auto stage = [&](int buf, int kt2) {
#pragma unroll
        for (int i = 0; i < 2; ++i) {
            const int tt = t + i * 256;
            const int row = tt >> 3;
            const int sl = (tt & 7) ^ (row & 7);
            char* kd = (char*)&KtS[buf][0] + w * 1024 + i * 4096;  // wave-uniform
            char* vd = (char*)&VtS[buf][0] + w * 1024 + i * 4096;
            gload_lds16(kbase + (size_t)(kt2 * 64 + row) * 64 + sl * 8, kd);
            gload_lds16(vbase + (size_t)row * 1024 + kt2 * 64 + sl * 8, vd);
        }
    };

    stage(0, 0);
    __syncthreads();

    for (int kt = 0; kt < 16; ++kt) {
        const int cur = kt & 1;
        if (kt < 15) stage(cur ^ 1, kt + 1);  // prefetch next tile (no wait)

        const char* KtC = (const char*)&KtS[cur][0];
        const char* VtC = (const char*)&VtS[cur][0];

        // S^T[key][q] = K . Q^T. s0: keys 0-31, s1: keys 32-63.
        f32x16 s0 = (f32x16)0.f, s1 = (f32x16)0.f;
        __builtin_amdgcn_s_setprio(1);
#pragma unroll
        for (int s = 0; s < 4; ++s) {
            const int colb = s * 32 + hi * 16;
            bf16x8 k0 = *(const bf16x8*)(KtC + ((lq * 128 + colb) ^ swz));
            bf16x8 k1 = *(const bf16x8*)(KtC + (((32 + lq) * 128 + colb) ^ swz));
            s0 = __builtin_amdgcn_mfma_f32_32x32x16_bf16(k0, qb[s], s0, 0, 0, 0);
            s1 = __builtin_amdgcn_mfma_f32_32x32x16_bf16(k1, qb[s], s1, 0, 0, 0);
        }
        __builtin_amdgcn_s_setprio(0);

        // Row max: lane-local tree + one pair-combine (l ^ 32).
        float ma = fmaxf(s0[0], s0[1]), mb = fmaxf(s0[2], s0[3]);
#pragma unroll
        for (int i = 4; i < 16; i += 4) {
            ma = fmaxf(ma, fmaxf(s0[i], s0[i + 1]));
            mb = fmaxf(mb, fmaxf(s0[i + 2], s0[i + 3]));
        }
#pragma unroll
        for (int i = 0; i < 16; i += 4) {
            ma = fmaxf(ma, fmaxf(s1[i], s1[i + 1]));
            mb = fmaxf(mb, fmaxf(s1[i + 2], s1[i + 3]));
        }
        float pmax = fmaxf(ma, mb);
        pmax = fmaxf(pmax, __shfl_xor(pmax, 32, 64));

        // Defer-max (T13): rescale only when running max grows by > 8.
        if (__any(pmax - m > 8.f)) {
            const float mn = fmaxf(m, pmax);
            const float corr = __expf(m - mn);
            m = mn;
            lsum *= corr;
#pragma unroll
            for (int i = 0; i < 16; ++i) { oacc[0][i] *= corr; oacc[1][i] *= corr; }
        }

        // P = exp(S - m) (<= e^8); lane-partial sums.
        float ls0 = 0.f, ls1 = 0.f;
#pragma unroll
        for (int i = 0; i < 16; ++i) { s0[i] = __expf(s0[i] - m); ls0 += s0[i]; }
#pragma unroll
        for (int i = 0; i < 16; ++i) { s1[i] = __expf(s1[i] - m); ls1 += s1[i]; }
        lsum += ls0 + ls1;

        // PV via quarter-P: per 16-key step, write lane's 8 keys (2x b64),
        // read B-frag (b128, conflict-free via 16B chunk-XOR), 2 MFMA.
        char* prow = (char*)&Pq[w][0] + lq * 32;
        const int csw = ((lq >> 2) & 1) << 4;
#pragma unroll
        for (int s = 0; s < 4; ++s) {
            const int rb = (s & 1) * 8;
            uint2 W0, W1;
            if (s < 2) {
                W0.x = pkbf(s0[rb + 0], s0[rb + 1]); W0.y = pkbf(s0[rb + 2], s0[rb + 3]);
                W1.x = pkbf(s0[rb + 4], s0[rb + 5]); W1.y = pkbf(s0[rb + 6], s0[rb + 7]);
            } else {
                W0.x = pkbf(s1[rb + 0], s1[rb + 1]); W0.y = pkbf(s1[rb + 2], s1[rb + 3]);
                W1.x = pkbf(s1[rb + 4], s1[rb + 5]); W1.y = pkbf(s1[rb + 6], s1[rb + 7]);
            }
            *(uint2*)(prow + (csw ^ 0) + 8 * hi) = W0;
            *(uint2*)(prow + (csw ^ 16) + 8 * hi) = W1;
            bf16x8 pf = *(const bf16x8*)(prow + (csw ^ (hi << 4)));
            const int colb = s * 32 + hi * 16;
            bf16x8 v0 = *(const bf16x8*)(VtC + ((lq * 128 + colb) ^ swz));
            bf16x8 v1 = *(const bf16x8*)(VtC + (((32 + lq) * 128 + colb) ^ swz));
            __builtin_amdgcn_s_setprio(1);
            oacc[0] = __builtin_amdgcn_mfma_f32_32x32x16_bf16(v0, pf, oacc[0], 0, 0, 0);
            oacc[1] = __builtin_amdgcn_mfma_f32_32x32x16_bf16(v1, pf, oacc[1], 0, 0, 0);
            __builtin_amdgcn_s_setprio(0);
        }

        __syncthreads();  // drains prefetch DMA + all reads of buffer `cur`
    }

    // Combine lane-partial sums across the (l, l^32) pair, normalize, store.
    lsum += __shfl_xor(lsum, 32, 64);
    const float inv = 1.f / lsum;
    const int b = bh >> 3, h = bh & 7;
    __hip_bfloat16* aop = ao + ((size_t)b * 1024 + qrow) * 512 + h * 64;
#pragma unroll
    for (int dd = 0; dd < 2; ++dd)
#pragma unroll
        for (int rg = 0; rg < 4; ++rg) {
            u16x4 pkd;
#pragma unroll
            for (int j = 0; j < 4; ++j)
                pkd[j] = bfbits(oacc[dd][rg * 4 + j] * inv);
            const int d0 = dd * 32 + rg * 8 + hi * 4;
            *(u16x4*)(aop + d0) = pkd;
        }
}

// ---------------------------------------------------------------------------
// Out projection + bias + residual in (B, C, N) layout. Unchanged.
// ---------------------------------------------------------------------------
__global__ __launch_bounds__(256) void out_gemm(
    const __hip_bfloat16* __restrict__ Wot,  // (512 c, 512 i)
    const __hip_bfloat16* __restrict__ ao,   // (B, 1024, 512)
    const float* __restrict__ bias,          // (512)
    const float* __restrict__ x,             // (B, 512, 1024)
    float* __restrict__ out) {               // (B, 512, 1024)
    __shared__ __attribute__((aligned(16))) __hip_bfloat16 Atile[128 * 64];
    __shared__ __attribute__((aligned(16))) __hip_bfloat16 Btile[128 * 64];
    const int tn = blockIdx.x;
    const int tc = blockIdx.y;
    const int b  = blockIdx.z;
    f32x4 acc[4][4];
    gemm128_tile(Wot + (size_t)tc * 128 * 512, 512,
                 ao + ((size_t)b * 1024 + tn * 128) * 512, 512, 512, Atile, Btile, acc);

    const int t = threadIdx.x, l = t & 63, w = t >> 6;
    const int wr = (w >> 1) * 64, wc = (w & 1) * 64, fr = l & 15, fq = l >> 4;
#pragma unroll
    for (int m = 0; m < 4; ++m) {
#pragma unroll
        for (int n = 0; n < 4; ++n) {
            const int nn = tn * 128 + wc + n * 16 + fr;
#pragma unroll
            for (int r = 0; r < 4; ++r) {
                const int c = tc * 128 + wr + m * 16 + fq * 4 + r;
                const size_t idx = ((size_t)b * 512 + c) * 1024 + nn;
                out[idx] = acc[m][n][r] + bias[c] + x[idx];
            }
        }
    }
}

// ---------------------------------------------------------------------------
extern "C" void kernel_launch(void* const* d_in, const int* in_sizes, int n_in,
                              void* d_out, int out_size, void* d_ws, size_t ws_size,
                              hipStream_t stream) {
    const float* x     = (const float*)d_in[0];
    const float* W_qkv = (const float*)d_in[1];
    const float* b_qkv = (const float*)d_in[2];
    const float* W_out = (const float*)d_in[3];
    const float* b_out = (const float*)d_in[4];
    float* out = (float*)d_out;

    const int B = 16, C = 512, N = 1024, BH = B * N_HEADS;

    char* ws = (char*)d_ws;
    __hip_bfloat16* xt   = (__hip_bfloat16*)ws; ws += (size_t)B * N * C * 2;
    __hip_bfloat16* Wqt  = (__hip_bfloat16*)ws; ws += (size_t)1536 * 512 * 2;
    __hip_bfloat16* Wot  = (__hip_bfloat16*)ws; ws += (size_t)512 * 512 * 2;
    __hip_bfloat16* q_ws = (__hip_bfloat16*)ws; ws += (size_t)BH * N * 64 * 2;
    __hip_bfloat16* k_ws = (__hip_bfloat16*)ws; ws += (size_t)BH * N * 64 * 2;
    __hip_bfloat16* v_ws = (__hip_bfloat16*)ws; ws += (size_t)BH * 64 * N * 2;
    __hip_bfloat16* ao   = (__hip_bfloat16*)ws; ws += (size_t)B * N * 512 * 2;

    transpose_bf16<<<dim3(N / 32, C / 32, B), dim3(32, 8), 0, stream>>>(x, xt, C, N);
    transpose_bf16<<<dim3(1536 / 32, 512 / 32, 1), dim3(32, 8), 0, stream>>>(W_qkv, Wqt, 512, 1536);
    transpose_bf16<<<dim3(512 / 32, 512 / 32, 1), dim3(32, 8), 0, stream>>>(W_out, Wot, 512, 512);

    qkv_gemm<<<dim3(12, 8, B), 256, 0, stream>>>(xt, Wqt, b_qkv, q_ws, k_ws, v_ws);

    attn_kernel<<<dim3(1024), 256, 0, stream>>>(q_ws, k_ws, v_ws, ao);

    out_gemm<<<dim3(8, 4, B), 256, 0, stream>>>(Wot, ao, b_out, x, out);
}